// Round 1
// baseline (371.495 us; speedup 1.0000x reference)
//
#include <hip/hip_runtime.h>

#define BB 32
#define NN 384
#define RR 16

__device__ __forceinline__ float softplus_f(float x) {
    // logaddexp(0, x) = max(x,0) + log1p(exp(-|x|))
    return fmaxf(x, 0.0f) + log1pf(expf(-fabsf(x)));
}

__device__ __forceinline__ float blockReduceSumF(float val, float* smem) {
    #pragma unroll
    for (int off = 32; off > 0; off >>= 1) val += __shfl_down(val, off, 64);
    int lane = threadIdx.x & 63;
    int wave = threadIdx.x >> 6;
    if (lane == 0) smem[wave] = val;
    __syncthreads();
    int nw = blockDim.x >> 6;
    if (wave == 0) {
        val = (lane < nw) ? smem[lane] : 0.0f;
        #pragma unroll
        for (int off = 32; off > 0; off >>= 1) val += __shfl_down(val, off, 64);
    }
    return val;
}

__device__ __forceinline__ int blockReduceSumI(int val, int* smem) {
    #pragma unroll
    for (int off = 32; off > 0; off >>= 1) val += __shfl_down(val, off, 64);
    int lane = threadIdx.x & 63;
    int wave = threadIdx.x >> 6;
    if (lane == 0) smem[wave] = val;
    __syncthreads();
    int nw = blockDim.x >> 6;
    if (wave == 0) {
        val = (lane < nw) ? smem[lane] : 0;
        #pragma unroll
        for (int off = 32; off > 0; off >>= 1) val += __shfl_down(val, off, 64);
    }
    return val;
}

// ---- Kernel 1: pairwise reading-order BCE, partial sums into ws[0..1] ----
__global__ void order_loss_kernel(const float* __restrict__ order_logits,
                                  const int* __restrict__ reading_orders,
                                  const unsigned char* __restrict__ region_mask,
                                  float* __restrict__ ws) {
    const int N4 = NN / 4;                 // 96 float4 per row
    const int total4 = BB * NN * N4;       // 1,179,648
    float sum = 0.0f;
    int cnt = 0;
    for (int idx = blockIdx.x * blockDim.x + threadIdx.x; idx < total4;
         idx += gridDim.x * blockDim.x) {
        int j4 = (idx % N4) * 4;
        int bi = idx / N4;                 // b*N + i
        int i  = bi % NN;
        int b  = bi / NN;
        if (!region_mask[bi]) continue;    // row invalid -> no contribution
        int ro_i = reading_orders[bi];
        float4 x4 = ((const float4*)order_logits)[idx];
        const int bBase = b * NN;
        #pragma unroll
        for (int k = 0; k < 4; ++k) {
            int j = j4 + k;
            float x = (&x4.x)[k];
            if (region_mask[bBase + j] && (i != j)) {
                float t = (ro_i < reading_orders[bBase + j]) ? 1.0f : 0.0f;
                sum += softplus_f(x) - x * t;
                cnt++;
            }
        }
    }
    __shared__ float sf[8];
    __shared__ int si[8];
    float bs = blockReduceSumF(sum, sf);
    int bc = blockReduceSumI(cnt, si);
    if (threadIdx.x == 0) {
        atomicAdd(&ws[0], bs);
        atomicAdd((int*)&ws[1], bc);
    }
}

// ---- Kernel 2: relation CE via gather, partial sums into ws[2..3] ----
__global__ void relation_loss_kernel(const float* __restrict__ relation_logits,
                                     const int* __restrict__ parent_ids,
                                     const int* __restrict__ relations,
                                     const unsigned char* __restrict__ region_mask,
                                     float* __restrict__ ws) {
    int t = blockIdx.x * blockDim.x + threadIdx.x;
    float sum = 0.0f;
    int cnt = 0;
    if (t < BB * NN) {
        int b = t / NN, i = t % NN;
        int p = parent_ids[t];
        int r = relations[t];
        if (region_mask[t] && p >= 0 && p < NN && r >= 0) {
            const float4* row =
                (const float4*)(relation_logits + ((size_t)(b * NN + p) * NN + i) * RR);
            float v[RR];
            float4 a0 = row[0], a1 = row[1], a2 = row[2], a3 = row[3];
            v[0]=a0.x; v[1]=a0.y; v[2]=a0.z; v[3]=a0.w;
            v[4]=a1.x; v[5]=a1.y; v[6]=a1.z; v[7]=a1.w;
            v[8]=a2.x; v[9]=a2.y; v[10]=a2.z; v[11]=a2.w;
            v[12]=a3.x; v[13]=a3.y; v[14]=a3.z; v[15]=a3.w;
            float m = v[0];
            #pragma unroll
            for (int k = 1; k < RR; ++k) m = fmaxf(m, v[k]);
            float s = 0.0f;
            #pragma unroll
            for (int k = 0; k < RR; ++k) s += expf(v[k] - m);
            float lse = m + logf(s);
            sum = lse - v[r];
            cnt = 1;
        }
    }
    __shared__ float sf[8];
    __shared__ int si[8];
    float bs = blockReduceSumF(sum, sf);
    int bc = blockReduceSumI(cnt, si);
    if (threadIdx.x == 0) {
        atomicAdd(&ws[2], bs);
        atomicAdd((int*)&ws[3], bc);
    }
}

// ---- Kernel 3: finalize the three scalars ----
__global__ void finalize_kernel(const float* __restrict__ ws, float* __restrict__ out) {
    if (threadIdx.x == 0) {
        float os = ws[0];
        int oc = ((const int*)ws)[1];
        float rs = ws[2];
        int rc = ((const int*)ws)[3];
        float order_loss = os / (float)(oc > 1 ? oc : 1);
        float rel_loss = rs / (float)(rc > 1 ? rc : 1);
        out[0] = 1.0f * order_loss + 0.5f * rel_loss;  // ORDER_W=1.0, REL_W=0.5
        out[1] = order_loss;
        out[2] = rel_loss;
    }
}

extern "C" void kernel_launch(void* const* d_in, const int* in_sizes, int n_in,
                              void* d_out, int out_size, void* d_ws, size_t ws_size,
                              hipStream_t stream) {
    const float* order_logits    = (const float*)d_in[0];
    const float* relation_logits = (const float*)d_in[1];
    const int* reading_orders    = (const int*)d_in[2];
    const int* parent_ids        = (const int*)d_in[3];
    const int* relations         = (const int*)d_in[4];
    const unsigned char* region_mask = (const unsigned char*)d_in[5];
    float* out = (float*)d_out;
    float* ws  = (float*)d_ws;

    hipMemsetAsync(ws, 0, 4 * sizeof(float), stream);

    order_loss_kernel<<<1024, 256, 0, stream>>>(order_logits, reading_orders,
                                                region_mask, ws);
    relation_loss_kernel<<<(BB * NN + 255) / 256, 256, 0, stream>>>(
        relation_logits, parent_ids, relations, region_mask, ws);
    finalize_kernel<<<1, 64, 0, stream>>>(ws, out);
}

// Round 2
// 349.141 us; speedup vs baseline: 1.0640x; 1.0640x over previous
//
#include <hip/hip_runtime.h>

#define BB 32
#define NN 384
#define RR 16
#define GRID_MAIN 768          // 3 blocks/CU on 256 CUs; 768*256*6 == 32*384*96 exactly
#define BLK 256

__device__ __forceinline__ float softplus_f(float x) {
    // logaddexp(0, x) = max(x,0) + log1p(exp(-|x|))
    return fmaxf(x, 0.0f) + log1pf(expf(-fabsf(x)));
}

// Reduce 4 lanes-worth of values (2 float, 2 int-in-float-bits) across the block.
// Returns in lane 0 of wave 0.
__device__ __forceinline__ void blockReduce4(float& f0, int& c0, float& f1, int& c1) {
    #pragma unroll
    for (int off = 32; off > 0; off >>= 1) {
        f0 += __shfl_down(f0, off, 64);
        c0 += __shfl_down(c0, off, 64);
        f1 += __shfl_down(f1, off, 64);
        c1 += __shfl_down(c1, off, 64);
    }
    __shared__ float sf0[16], sf1[16];
    __shared__ int   sc0[16], sc1[16];
    int lane = threadIdx.x & 63;
    int wave = threadIdx.x >> 6;
    if (lane == 0) { sf0[wave] = f0; sc0[wave] = c0; sf1[wave] = f1; sc1[wave] = c1; }
    __syncthreads();
    int nw = blockDim.x >> 6;
    if (wave == 0) {
        f0 = (lane < nw) ? sf0[lane] : 0.0f;
        c0 = (lane < nw) ? sc0[lane] : 0;
        f1 = (lane < nw) ? sf1[lane] : 0.0f;
        c1 = (lane < nw) ? sc1[lane] : 0;
        #pragma unroll
        for (int off = 32; off > 0; off >>= 1) {
            f0 += __shfl_down(f0, off, 64);
            c0 += __shfl_down(c0, off, 64);
            f1 += __shfl_down(f1, off, 64);
            c1 += __shfl_down(c1, off, 64);
        }
    }
}

// ---- Main fused kernel: order BCE (all threads) + relation CE (first B*N threads).
// Per-block partials written to ws[blockIdx.x] as float4 {oSum, oCnt(bits), rSum, rCnt(bits)}.
__global__ __launch_bounds__(BLK) void main_loss_kernel(
        const float* __restrict__ order_logits,
        const float* __restrict__ relation_logits,
        const int* __restrict__ reading_orders,
        const int* __restrict__ parent_ids,
        const int* __restrict__ relations,
        const unsigned char* __restrict__ region_mask,
        float4* __restrict__ ws) {
    const int N4 = NN / 4;                  // 96 float4 per row
    const int total4 = BB * NN * N4;        // 1,179,648
    const int gid = blockIdx.x * BLK + threadIdx.x;

    float oSum = 0.0f; int oCnt = 0;
    for (int idx = gid; idx < total4; idx += GRID_MAIN * BLK) {
        int j4 = (idx % N4) * 4;
        int bi = idx / N4;                  // b*N + i
        if (!region_mask[bi]) continue;     // row invalid -> no contribution
        int i  = bi % NN;
        int bBase = bi - i;                 // b*NN
        int ro_i = reading_orders[bi];
        float4 x4 = ((const float4*)order_logits)[idx];
        #pragma unroll
        for (int k = 0; k < 4; ++k) {
            int j = j4 + k;
            float x = (&x4.x)[k];
            if (region_mask[bBase + j] && (i != j)) {
                float t = (ro_i < reading_orders[bBase + j]) ? 1.0f : 0.0f;
                oSum += softplus_f(x) - x * t;
                oCnt++;
            }
        }
    }

    float rSum = 0.0f; int rCnt = 0;
    if (gid < BB * NN) {
        int b = gid / NN, i = gid % NN;
        int p = parent_ids[gid];
        int r = relations[gid];
        if (region_mask[gid] && p >= 0 && p < NN && r >= 0) {
            const float4* row =
                (const float4*)(relation_logits + ((size_t)(b * NN + p) * NN + i) * RR);
            float v[RR];
            float4 a0 = row[0], a1 = row[1], a2 = row[2], a3 = row[3];
            v[0]=a0.x;  v[1]=a0.y;  v[2]=a0.z;  v[3]=a0.w;
            v[4]=a1.x;  v[5]=a1.y;  v[6]=a1.z;  v[7]=a1.w;
            v[8]=a2.x;  v[9]=a2.y;  v[10]=a2.z; v[11]=a2.w;
            v[12]=a3.x; v[13]=a3.y; v[14]=a3.z; v[15]=a3.w;
            float m = v[0];
            #pragma unroll
            for (int k = 1; k < RR; ++k) m = fmaxf(m, v[k]);
            float s = 0.0f;
            #pragma unroll
            for (int k = 0; k < RR; ++k) s += expf(v[k] - m);
            rSum = m + logf(s) - v[r];
            rCnt = 1;
        }
    }

    blockReduce4(oSum, oCnt, rSum, rCnt);
    if (threadIdx.x == 0) {
        float4 out;
        out.x = oSum;
        out.y = __int_as_float(oCnt);
        out.z = rSum;
        out.w = __int_as_float(rCnt);
        ws[blockIdx.x] = out;   // overwrites 0xAA poison; no memset needed
    }
}

// ---- Finalize: reduce GRID_MAIN per-block partials, emit 3 scalars ----
__global__ __launch_bounds__(BLK) void finalize_kernel(const float4* __restrict__ ws,
                                                       float* __restrict__ out) {
    float oSum = 0.0f, rSum = 0.0f;
    int oCnt = 0, rCnt = 0;
    for (int i = threadIdx.x; i < GRID_MAIN; i += BLK) {
        float4 v = ws[i];
        oSum += v.x;
        oCnt += __float_as_int(v.y);
        rSum += v.z;
        rCnt += __float_as_int(v.w);
    }
    blockReduce4(oSum, oCnt, rSum, rCnt);
    if (threadIdx.x == 0) {
        float order_loss = oSum / (float)(oCnt > 1 ? oCnt : 1);
        float rel_loss   = rSum / (float)(rCnt > 1 ? rCnt : 1);
        out[0] = 1.0f * order_loss + 0.5f * rel_loss;  // ORDER_W=1.0, REL_W=0.5
        out[1] = order_loss;
        out[2] = rel_loss;
    }
}

extern "C" void kernel_launch(void* const* d_in, const int* in_sizes, int n_in,
                              void* d_out, int out_size, void* d_ws, size_t ws_size,
                              hipStream_t stream) {
    const float* order_logits    = (const float*)d_in[0];
    const float* relation_logits = (const float*)d_in[1];
    const int* reading_orders    = (const int*)d_in[2];
    const int* parent_ids        = (const int*)d_in[3];
    const int* relations         = (const int*)d_in[4];
    const unsigned char* region_mask = (const unsigned char*)d_in[5];
    float* out  = (float*)d_out;
    float4* ws4 = (float4*)d_ws;

    main_loss_kernel<<<GRID_MAIN, BLK, 0, stream>>>(
        order_logits, relation_logits, reading_orders, parent_ids, relations,
        region_mask, ws4);
    finalize_kernel<<<1, BLK, 0, stream>>>(ws4, out);
}